// Round 5
// baseline (5095.873 us; speedup 1.0000x reference)
//
#include <hip/hip_runtime.h>
#include <math.h>

typedef float f4x __attribute__((ext_vector_type(4)));

#define B_    128
#define T_ENC 40
#define T_DEC 27
#define T_ALL 67
#define HID_  512
#define G3_   1536
#define EMB_  1024
#define V_    20000
#define NBLK  512

__device__ __forceinline__ float sigmoidf_(float x) { return 1.f / (1.f + expf(-x)); }

// ---------------- tree grid barrier: 16 leaves x 32 + root, monotone counters ----------------
__device__ __forceinline__ void gbar(unsigned* bars, unsigned barno) {
  __syncthreads();
  if (threadIdx.x == 0) {
    __threadfence();  // release our h writes
    unsigned g = blockIdx.x >> 5;               // 16 groups of 32 blocks
    unsigned* leaf = bars + (size_t)g * 32;     // 128B apart
    unsigned* root = bars + 512;
    unsigned* gen  = bars + 544;
    if (__hip_atomic_fetch_add(leaf, 1u, __ATOMIC_RELAXED, __HIP_MEMORY_SCOPE_AGENT) == barno * 32u - 1u) {
      if (__hip_atomic_fetch_add(root, 1u, __ATOMIC_RELAXED, __HIP_MEMORY_SCOPE_AGENT) == barno * 16u - 1u) {
        __hip_atomic_store(gen, barno, __ATOMIC_RELEASE, __HIP_MEMORY_SCOPE_AGENT);
      }
    }
    while (__hip_atomic_load(gen, __ATOMIC_RELAXED, __HIP_MEMORY_SCOPE_AGENT) < barno) {
      __builtin_amdgcn_s_sleep(1);
    }
    __threadfence();  // acquire before reading others' h
  }
  __syncthreads();
}

// ---------------- gather decoder word embeddings ----------------
__global__ __launch_bounds__(128) void k_gather(const int* __restrict__ target,
                                                const float* __restrict__ E,
                                                float* __restrict__ words) {
  int m = blockIdx.x;
  int b = m / T_DEC, t = m % T_DEC;
  int idx = target[b * 28 + t];
  const float4* src = reinterpret_cast<const float4*>(E + (size_t)idx * HID_);
  float4* dst = reinterpret_cast<float4*>(words + (size_t)m * HID_);
  dst[threadIdx.x] = src[threadIdx.x];
}

// ---------------- fp32 GEMM, row-major C (projection) ----------------
__global__ __launch_bounds__(256) void k_gemm(const float* __restrict__ A, int lda,
                                              const float* __restrict__ Bm, int ldb, int boff,
                                              const float* __restrict__ bias,
                                              float* __restrict__ C, int ldc,
                                              int N, int K) {
  __shared__ float As[16][128];
  __shared__ float Bs[16][128];
  const int tid = threadIdx.x;
  const int m0 = blockIdx.y * 128;
  const int n0 = blockIdx.x * 128;
  const int tx = tid & 15, ty = tid >> 4;
  float acc[8][8];
#pragma unroll
  for (int i = 0; i < 8; ++i)
#pragma unroll
    for (int j = 0; j < 8; ++j) acc[i][j] = 0.f;

  for (int k0 = 0; k0 < K; k0 += 16) {
#pragma unroll
    for (int i = 0; i < 2; ++i) {
      int v = tid * 2 + i;
      int row = v >> 2;
      int kv = (v & 3) << 2;
      float4 a4 = *reinterpret_cast<const float4*>(&A[(size_t)(m0 + row) * lda + k0 + kv]);
      As[kv + 0][row] = a4.x; As[kv + 1][row] = a4.y; As[kv + 2][row] = a4.z; As[kv + 3][row] = a4.w;
      int nr = n0 + row;
      float4 b4 = make_float4(0.f, 0.f, 0.f, 0.f);
      if (nr < N) b4 = *reinterpret_cast<const float4*>(&Bm[(size_t)nr * ldb + boff + k0 + kv]);
      Bs[kv + 0][row] = b4.x; Bs[kv + 1][row] = b4.y; Bs[kv + 2][row] = b4.z; Bs[kv + 3][row] = b4.w;
    }
    __syncthreads();
#pragma unroll
    for (int kk = 0; kk < 16; ++kk) {
      float a[8], bb[8];
      *reinterpret_cast<float4*>(&a[0]) = *reinterpret_cast<const float4*>(&As[kk][ty * 8]);
      *reinterpret_cast<float4*>(&a[4]) = *reinterpret_cast<const float4*>(&As[kk][ty * 8 + 4]);
      *reinterpret_cast<float4*>(&bb[0]) = *reinterpret_cast<const float4*>(&Bs[kk][tx * 8]);
      *reinterpret_cast<float4*>(&bb[4]) = *reinterpret_cast<const float4*>(&Bs[kk][tx * 8 + 4]);
#pragma unroll
      for (int i = 0; i < 8; ++i)
#pragma unroll
        for (int j = 0; j < 8; ++j) acc[i][j] += a[i] * bb[j];
    }
    __syncthreads();
  }
#pragma unroll
  for (int i = 0; i < 8; ++i) {
    int m = m0 + ty * 8 + i;
    int n = n0 + tx * 8;
    if (n < N) {
      float* cp = &C[(size_t)m * ldc + n];
#pragma unroll
      for (int j = 0; j < 8; ++j) cp[j] = acc[i][j] + bias[n + j];
    }
  }
}

// ---------------- fp32 GEMM, transposed scatter-store: Ct[(t*1536+n)*128 + b], m = b*TT+t ----
__global__ __launch_bounds__(256) void k_gemm_t(const float* __restrict__ A, int lda,
                                                const float* __restrict__ Bm, int ldb, int boff,
                                                const float* __restrict__ bias,
                                                float* __restrict__ Ct, int TT, int K) {
  __shared__ float As[16][128];
  __shared__ float Bs[16][128];
  const int tid = threadIdx.x;
  const int m0 = blockIdx.y * 128;
  const int n0 = blockIdx.x * 128;
  const int tx = tid & 15, ty = tid >> 4;
  float acc[8][8];
#pragma unroll
  for (int i = 0; i < 8; ++i)
#pragma unroll
    for (int j = 0; j < 8; ++j) acc[i][j] = 0.f;

  for (int k0 = 0; k0 < K; k0 += 16) {
#pragma unroll
    for (int i = 0; i < 2; ++i) {
      int v = tid * 2 + i;
      int row = v >> 2;
      int kv = (v & 3) << 2;
      float4 a4 = *reinterpret_cast<const float4*>(&A[(size_t)(m0 + row) * lda + k0 + kv]);
      As[kv + 0][row] = a4.x; As[kv + 1][row] = a4.y; As[kv + 2][row] = a4.z; As[kv + 3][row] = a4.w;
      float4 b4 = *reinterpret_cast<const float4*>(&Bm[(size_t)(n0 + row) * ldb + boff + k0 + kv]);
      Bs[kv + 0][row] = b4.x; Bs[kv + 1][row] = b4.y; Bs[kv + 2][row] = b4.z; Bs[kv + 3][row] = b4.w;
    }
    __syncthreads();
#pragma unroll
    for (int kk = 0; kk < 16; ++kk) {
      float a[8], bb[8];
      *reinterpret_cast<float4*>(&a[0]) = *reinterpret_cast<const float4*>(&As[kk][ty * 8]);
      *reinterpret_cast<float4*>(&a[4]) = *reinterpret_cast<const float4*>(&As[kk][ty * 8 + 4]);
      *reinterpret_cast<float4*>(&bb[0]) = *reinterpret_cast<const float4*>(&Bs[kk][tx * 8]);
      *reinterpret_cast<float4*>(&bb[4]) = *reinterpret_cast<const float4*>(&Bs[kk][tx * 8 + 4]);
#pragma unroll
      for (int i = 0; i < 8; ++i)
#pragma unroll
        for (int j = 0; j < 8; ++j) acc[i][j] += a[i] * bb[j];
    }
    __syncthreads();
  }
#pragma unroll
  for (int i = 0; i < 8; ++i) {
    int m = m0 + ty * 8 + i;
    int b = m / TT, tt = m - b * TT;
    float* cp = &Ct[((size_t)tt * G3_ + n0 + tx * 8) * 128 + b];
#pragma unroll
    for (int j = 0; j < 8; ++j) cp[(size_t)j * 128] = acc[i][j] + bias[n0 + tx * 8 + j];
  }
}

// ---------------- persistent recurrence: 512 blocks = 256 unit-groups x 2 batch-halves ----------------
// Block owns units {2*ug, 2*ug+1} and batches [bg*64, bg*64+64). 72 KB LDS -> 2 blocks/CU, 2 waves/SIMD.
// Per phase p: gh1,gi2 from h1[p+1]; gh2 from h2[p]; -> h1[p+2], h2[p+1]. One grid barrier per phase.
__global__ __launch_bounds__(256, 2) void k_recur(
    const float* __restrict__ G1t, const float* __restrict__ GWt,
    const float* __restrict__ W_hh1, const float* __restrict__ W_ih2, const float* __restrict__ W_hh2,
    const float* __restrict__ b_hh1, const float* __restrict__ b_hh2,
    const float* __restrict__ b_ih1, const float* __restrict__ b_ih2,
    float* h1x, float* h1y, float* h2x, float* h2y,
    float* __restrict__ h2seq, unsigned* bars) {
  __shared__ float Wlds[18 * 516];   // rows: mat*6 + g*2 + uu  (mat 0=W_hh1, 1=W_ih2[:,:512], 2=W_hh2)
  __shared__ float Hs1[64 * 68];     // h1[p+1] chunk, block-local b 0..63, [b][64k + pad4]
  __shared__ float Hs2[64 * 68];     // h2[p]   chunk

  const int tid = threadIdx.x;
  const int bid = blockIdx.x;
  const int ug = bid >> 1;           // unit-group 0..255
  const int bg = bid & 1;            // batch half
  const int u0 = ug * 2;
  const int bbase = bg * 64;
  const int wid = tid >> 6;
  const int lane = tid & 63;
  const int kq = lane & 7;           // k-octet within 64-chunk
  const int cc = lane >> 3;          // b-lane within bi-group
  const int uu = wid & 1;
  const int bh = wid >> 1;           // which 32-b half of the block's 64
  const int ugl = u0 + uu;
  // epilogue: lanes kq<4 keep b = bbase + bh*32 + kq*8 + cc (kq&3 keeps addresses in-range for all lanes)
  const int myb = bbase + bh * 32 + (kq & 3) * 8 + cc;

  // ---- pin weights in LDS (once) ----
  for (int idx = tid; idx < 18 * 128; idx += 256) {
    int row = idx >> 7; int c4 = (idx & 127) << 2;
    int mm = row / 6, rem = row - mm * 6; int g = rem >> 1, ur = rem & 1;
    int grow = g * HID_ + u0 + ur;
    const float* src = (mm == 0) ? (W_hh1 + (size_t)grow * HID_ + c4)
                     : (mm == 1) ? (W_ih2 + (size_t)grow * EMB_ + c4)
                                 : (W_hh2 + (size_t)grow * HID_ + c4);
    *reinterpret_cast<f4x*>(&Wlds[row * 516 + c4]) = *reinterpret_cast<const f4x*>(src);
  }
  const float bh1r = b_hh1[ugl], bh1z = b_hh1[HID_ + ugl], bh1n = b_hh1[2 * HID_ + ugl];
  const float bh2r = b_hh2[ugl], bh2z = b_hh2[HID_ + ugl], bh2n = b_hh2[2 * HID_ + ugl];
  const float bi1r = b_ih1[ugl], bi1z = b_ih1[HID_ + ugl], bi1n = b_ih1[2 * HID_ + ugl];
  const float bi2r = b_ih2[ugl], bi2z = b_ih2[HID_ + ugl], bi2n = b_ih2[2 * HID_ + ugl];

  // ---- prologue: h1[1] = GRU1(h1=0, x0): gh1 = bias only ----
  if (kq < 4) {
    float gr = G1t[(size_t)ugl * 128 + myb];
    float gz = G1t[(size_t)(HID_ + ugl) * 128 + myb];
    float gn = G1t[(size_t)(2 * HID_ + ugl) * 128 + myb];
    float r = sigmoidf_(gr + bh1r);
    float z = sigmoidf_(gz + bh1z);
    float n = tanhf(gn + r * bh1n);
    h1x[(size_t)myb * HID_ + ugl] = (1.f - z) * n;
  }
  gbar(bars, 1u);

  for (int p = 0; p < T_ALL; ++p) {
    const float* h1cur = (p & 1) ? h1y : h1x;
    float*       h1nxt = (p & 1) ? h1x : h1y;
    const float* h2cur = (p & 1) ? h2y : h2x;
    float*       h2nxt = (p & 1) ? h2x : h2y;

    // gate + h-scalar prefetch (independent of staged GEMM)
    float a_gr, a_gz, a_gn, b_xr, b_xz, b_xn;
    if (p + 1 < T_ENC) {
      const float* gp = G1t + (size_t)(p + 1) * G3_ * 128;
      a_gr = gp[(size_t)ugl * 128 + myb];
      a_gz = gp[(size_t)(HID_ + ugl) * 128 + myb];
      a_gn = gp[(size_t)(2 * HID_ + ugl) * 128 + myb];
    } else { a_gr = bi1r; a_gz = bi1z; a_gn = bi1n; }
    if (p < T_ENC) { b_xr = bi2r; b_xz = bi2z; b_xn = bi2n; }
    else {
      const float* gp = GWt + (size_t)(p - T_ENC) * G3_ * 128;
      b_xr = gp[(size_t)ugl * 128 + myb];
      b_xz = gp[(size_t)(HID_ + ugl) * 128 + myb];
      b_xn = gp[(size_t)(2 * HID_ + ugl) * 128 + myb];
    }
    float h1p = h1cur[(size_t)myb * HID_ + ugl];
    float h2p = h2cur[(size_t)myb * HID_ + ugl];

    float acc[4][3][3];
#pragma unroll
    for (int bi = 0; bi < 4; ++bi)
#pragma unroll
      for (int mm = 0; mm < 3; ++mm)
#pragma unroll
        for (int g = 0; g < 3; ++g) acc[bi][mm][g] = 0.f;

    f4x p1[4], p2[4];
    for (int ch = 0; ch < 8; ++ch) {
      if (ch == 0) {
#pragma unroll
        for (int i = 0; i < 4; ++i) {
          int v = i * 256 + tid; int b = v >> 4; int kf = v & 15;
          p1[i] = *reinterpret_cast<const f4x*>(&h1cur[(size_t)(bbase + b) * HID_ + kf * 4]);
          p2[i] = *reinterpret_cast<const f4x*>(&h2cur[(size_t)(bbase + b) * HID_ + kf * 4]);
        }
#pragma unroll
        for (int i = 0; i < 4; ++i) {
          int v = i * 256 + tid; int b = v >> 4; int kf = v & 15;
          *reinterpret_cast<f4x*>(&Hs1[b * 68 + kf * 4]) = p1[i];
          *reinterpret_cast<f4x*>(&Hs2[b * 68 + kf * 4]) = p2[i];
        }
        __syncthreads();
      }
      if (ch < 7) {  // prefetch next chunk into registers
#pragma unroll
        for (int i = 0; i < 4; ++i) {
          int v = i * 256 + tid; int b = v >> 4; int kf = v & 15;
          p1[i] = *reinterpret_cast<const f4x*>(&h1cur[(size_t)(bbase + b) * HID_ + (ch + 1) * 64 + kf * 4]);
          p2[i] = *reinterpret_cast<const f4x*>(&h2cur[(size_t)(bbase + b) * HID_ + (ch + 1) * 64 + kf * 4]);
        }
      }
      // compute chunk ch
#pragma unroll
      for (int jj = 0; jj < 2; ++jj) {
        const int ko = kq * 8 + jj * 4;
        f4x w[9];
#pragma unroll
        for (int r9 = 0; r9 < 9; ++r9) {
          int mm = r9 / 3, g = r9 - mm * 3;
          w[r9] = *reinterpret_cast<const f4x*>(&Wlds[(mm * 6 + g * 2 + uu) * 516 + ch * 64 + ko]);
        }
#pragma unroll
        for (int bi = 0; bi < 4; ++bi) {
          const int bl = bh * 32 + bi * 8 + cc;   // bank-uniform: 68*(bi*8) % 32 == 0, cc spreads
          f4x h1v = *reinterpret_cast<const f4x*>(&Hs1[bl * 68 + ko]);
          f4x h2v = *reinterpret_cast<const f4x*>(&Hs2[bl * 68 + ko]);
#pragma unroll
          for (int g = 0; g < 3; ++g) {
#pragma unroll
            for (int e = 0; e < 4; ++e) {
              acc[bi][0][g] += w[g][e] * h1v[e];
              acc[bi][1][g] += w[3 + g][e] * h1v[e];
              acc[bi][2][g] += w[6 + g][e] * h2v[e];
            }
          }
        }
      }
      if (ch < 7) {
        __syncthreads();
#pragma unroll
        for (int i = 0; i < 4; ++i) {
          int v = i * 256 + tid; int b = v >> 4; int kf = v & 15;
          *reinterpret_cast<f4x*>(&Hs1[b * 68 + kf * 4]) = p1[i];
          *reinterpret_cast<f4x*>(&Hs2[b * 68 + kf * 4]) = p2[i];
        }
        __syncthreads();
      }
    }

    // butterfly k-reduction over kq lanes (masks 1,2,4); lane kq==bi (kq<4) keeps b = bh*32 + bi*8 + cc
    float og[3][3];
#pragma unroll
    for (int bi = 0; bi < 4; ++bi)
#pragma unroll
      for (int mm = 0; mm < 3; ++mm)
#pragma unroll
        for (int g = 0; g < 3; ++g) {
          float s = acc[bi][mm][g];
          s += __shfl_xor(s, 1); s += __shfl_xor(s, 2); s += __shfl_xor(s, 4);
          if (kq == bi) og[mm][g] = s;
        }

    if (kq < 4) {
      // A-combine: h1[p+2]  (t_A = p+1)
      if (p + 1 < T_ALL) {
        float r = sigmoidf_(a_gr + og[0][0] + bh1r);
        float z = sigmoidf_(a_gz + og[0][1] + bh1z);
        float n = tanhf(a_gn + r * (og[0][2] + bh1n));
        h1nxt[(size_t)myb * HID_ + ugl] = (1.f - z) * n + z * h1p;
      }
      // B-combine: h2[p+1]  (t_B = p)
      {
        float r = sigmoidf_(b_xr + og[1][0] + og[2][0] + bh2r);
        float z = sigmoidf_(b_xz + og[1][1] + og[2][1] + bh2z);
        float n = tanhf(b_xn + og[1][2] + r * (og[2][2] + bh2n));
        float hv = (1.f - z) * n + z * h2p;
        h2nxt[(size_t)myb * HID_ + ugl] = hv;
        if (p >= T_ENC) h2seq[((size_t)myb * T_DEC + (p - T_ENC)) * HID_ + ugl] = hv;
      }
    }

    if (p + 1 < T_ALL) gbar(bars, 2u + (unsigned)p);
  }
}

// ---------------- log-softmax over rows of 20000 (in place on d_out) ----------------
__global__ __launch_bounds__(256) void k_logsoftmax(float* __restrict__ out) {
  float* row = out + (size_t)blockIdx.x * V_;
  const int tid = threadIdx.x;
  float mx = -INFINITY, s = 0.f;
  for (int i = tid; i < V_; i += 256) {
    float x = row[i];
    if (x > mx) { s = s * expf(mx - x) + 1.f; mx = x; }
    else        { s += expf(x - mx); }
  }
#pragma unroll
  for (int o = 1; o < 64; o <<= 1) {
    float omx = __shfl_xor(mx, o);
    float os  = __shfl_xor(s, o);
    float M = fmaxf(mx, omx);
    s = s * expf(mx - M) + os * expf(omx - M);
    mx = M;
  }
  __shared__ float smx[4], ss[4];
  int wid = tid >> 6, lane = tid & 63;
  if (lane == 0) { smx[wid] = mx; ss[wid] = s; }
  __syncthreads();
  if (tid == 0) {
    float M = smx[0]; float S = ss[0];
#pragma unroll
    for (int w = 1; w < 4; ++w) {
      float M2 = fmaxf(M, smx[w]);
      S = S * expf(M - M2) + ss[w] * expf(smx[w] - M2);
      M = M2;
    }
    ss[0] = logf(S) + M;
  }
  __syncthreads();
  float lse = ss[0];
  for (int i = tid; i < V_; i += 256) row[i] -= lse;
}

// ---------------- host launch ----------------
extern "C" void kernel_launch(void* const* d_in, const int* in_sizes, int n_in,
                              void* d_out, int out_size, void* d_ws, size_t ws_size,
                              hipStream_t stream) {
  const float* input = (const float*)d_in[0];
  const int*   target = (const int*)d_in[1];
  const float* W_ih1 = (const float*)d_in[2];
  const float* W_hh1 = (const float*)d_in[3];
  const float* b_ih1 = (const float*)d_in[4];
  const float* b_hh1 = (const float*)d_in[5];
  const float* W_ih2 = (const float*)d_in[6];
  const float* W_hh2 = (const float*)d_in[7];
  const float* b_ih2 = (const float*)d_in[8];
  const float* b_hh2 = (const float*)d_in[9];
  const float* E     = (const float*)d_in[10];
  const float* W_out = (const float*)d_in[11];
  const float* b_out = (const float*)d_in[12];
  float* out = (float*)d_out;

  float* ws = (float*)d_ws;
  float* G1t   = ws; ws += (size_t)T_ENC * G3_ * 128;   // [t][gate_row][b]
  float* GWt   = ws; ws += (size_t)T_DEC * G3_ * 128;   // [t][gate_row][b]
  float* words = ws; ws += (size_t)B_ * T_DEC * HID_;   // rows m = b*27+t
  float* h2seq = ws; ws += (size_t)B_ * T_DEC * HID_;   // [b][t][512]
  float* h1x = ws; ws += B_ * HID_;
  float* h1y = ws; ws += B_ * HID_;
  float* h2x = ws; ws += B_ * HID_;                     // h2x + bars contiguous -> one memset
  unsigned* bars = (unsigned*)ws; ws += 1024;           // leaves@[g*32], root@[512], gen@[544]
  float* h2y = ws; ws += B_ * HID_;

  hipMemsetAsync(h2x, 0, (size_t)B_ * HID_ * sizeof(float) + 4096, stream);

  k_gather<<<B_ * T_DEC, 128, 0, stream>>>(target, E, words);
  k_gemm_t<<<dim3(12, T_ENC), 256, 0, stream>>>(input, EMB_, W_ih1, EMB_, 0, b_ih1, G1t, T_ENC, EMB_);
  k_gemm_t<<<dim3(12, T_DEC), 256, 0, stream>>>(words, HID_, W_ih2, EMB_, HID_, b_ih2, GWt, T_DEC, HID_);

  k_recur<<<NBLK, 256, 0, stream>>>(G1t, GWt, W_hh1, W_ih2, W_hh2, b_hh1, b_hh2, b_ih1, b_ih2,
                                    h1x, h1y, h2x, h2y, h2seq, bars);

  k_gemm<<<dim3((V_ + 127) / 128, (B_ * T_DEC) / 128), 256, 0, stream>>>(
      h2seq, HID_, W_out, HID_, 0, b_out, out, V_, V_, HID_);
  k_logsoftmax<<<B_ * T_DEC, 256, 0, stream>>>(out);
}